// Round 8
// baseline (189.282 us; speedup 1.0000x reference)
//
#include <hip/hip_runtime.h>
#include <hip/hip_bf16.h>

// Problem constants (fixed by the reference setup)
#define H_DIM  128
#define NGRAPH 8192
#define NTOTAL 409600

typedef __attribute__((ext_vector_type(8))) short    s16x8;   // 8 bf16
typedef __attribute__((ext_vector_type(4))) float    f32x4;   // MFMA accumulator
typedef __attribute__((ext_vector_type(4))) unsigned u32x4;

__device__ __forceinline__ unsigned short f2bf(float f) {
    unsigned int u = __float_as_uint(f);
    unsigned int r = u + 0x7fffu + ((u >> 16) & 1u);   // RNE
    return (unsigned short)(r >> 16);
}

// ---------------- K0: W2 f32 -> bf16 (row-major [h][k]) ----------------
__global__ void k0_w2(const float* __restrict__ W2w, unsigned short* __restrict__ w2bf) {
    int i = blockIdx.x * 256 + threadIdx.x;   // grid covers exactly 128*128
    w2bf[i] = f2bf(W2w[i]);
}

// ---------------- K1: a_g = v_n @ W1^T + (W1_b + W2_b); zero s_g -------
__global__ __launch_bounds__(128) void k1_ag(
    const float* __restrict__ node_emb,
    const int*   __restrict__ last_idx,
    const float* __restrict__ W1w,
    const float* __restrict__ W1b,
    const float* __restrict__ W2b,
    float* __restrict__ a_g,
    float* __restrict__ s_g)
{
    __shared__ float vn[4][H_DIM];
    const int tid = threadIdx.x;
    const int g0  = blockIdx.x * 4;
    #pragma unroll
    for (int g = 0; g < 4; g++) {
        int li = last_idx[g0 + g];
        vn[g][tid] = node_emb[(size_t)li * H_DIM + tid];
        s_g[(size_t)(g0 + g) * H_DIM + tid] = 0.f;   // zero-init for k2 atomics
    }
    __syncthreads();
    float b = W1b[tid] + W2b[tid];
    float a0 = b, a1 = b, a2 = b, a3 = b;
    const float* wrow = W1w + (size_t)tid * H_DIM;
    #pragma unroll 8
    for (int k = 0; k < H_DIM; k += 4) {
        float4 w = *reinterpret_cast<const float4*>(wrow + k);
        a0 += w.x * vn[0][k] + w.y * vn[0][k+1] + w.z * vn[0][k+2] + w.w * vn[0][k+3];
        a1 += w.x * vn[1][k] + w.y * vn[1][k+1] + w.z * vn[1][k+2] + w.w * vn[1][k+3];
        a2 += w.x * vn[2][k] + w.y * vn[2][k+1] + w.z * vn[2][k+2] + w.w * vn[2][k+3];
        a3 += w.x * vn[3][k] + w.y * vn[3][k+1] + w.z * vn[3][k+2] + w.w * vn[3][k+3];
    }
    a_g[(size_t)(g0 + 0) * H_DIM + tid] = a0;
    a_g[(size_t)(g0 + 1) * H_DIM + tid] = a1;
    a_g[(size_t)(g0 + 2) * H_DIM + tid] = a2;
    a_g[(size_t)(g0 + 3) * H_DIM + tid] = a3;
}

// ---------------- K2: fused alpha + segment-sum, ZERO LDS --------------
// 6400 blocks x 256 threads (4 independent waves, no barrier). Each wave
// owns 16 nodes. W2 B-fragments come straight from global (L1/L2-hot).
__global__ __launch_bounds__(256, 6) void k2_fused(
    const float* __restrict__ node_emb,
    const float* __restrict__ num_count,
    const int*   __restrict__ seg_ids,
    const float* __restrict__ a_g,
    const unsigned short* __restrict__ w2bf,
    const float* __restrict__ q_w,
    const float* __restrict__ q_b,
    float* __restrict__ s_g)
{
    const int tid  = threadIdx.x;
    const int lane = tid & 63;
    const int l16 = lane & 15, lq = lane >> 4;
    const int nb  = (blockIdx.x * 4 + (tid >> 6)) * 16;   // this wave's 16 nodes

    // --- per-row scalars (row = l16) ---
    const int   sgl = seg_ids[nb + l16];
    const float ncl = num_count[nb + l16];
    const float qb0 = q_b[0];

    // --- A/B node fragments: row l16, cols lq*8 + ks*32 .. +7 (bf16) ---
    s16x8 af[4];
    const float* nrow = node_emb + (size_t)(nb + l16) * H_DIM + lq * 8;
    #pragma unroll
    for (int ks = 0; ks < 4; ks++) {
        float4 f0 = *reinterpret_cast<const float4*>(nrow + ks * 32);
        float4 f1 = *reinterpret_cast<const float4*>(nrow + ks * 32 + 4);
        unsigned p0, p1, p2, p3;
        asm("v_cvt_pk_bf16_f32 %0, %1, %2" : "=v"(p0) : "v"(f0.x), "v"(f0.y));
        asm("v_cvt_pk_bf16_f32 %0, %1, %2" : "=v"(p1) : "v"(f0.z), "v"(f0.w));
        asm("v_cvt_pk_bf16_f32 %0, %1, %2" : "=v"(p2) : "v"(f1.x), "v"(f1.y));
        asm("v_cvt_pk_bf16_f32 %0, %1, %2" : "=v"(p3) : "v"(f1.z), "v"(f1.w));
        union { u32x4 u; s16x8 s; } cv;
        cv.u = u32x4{p0, p1, p2, p3};
        af[ks] = cv.s;
    }

    // --- swapped z-MFMA: lane holds z[l16][h], h = nt*16 + lq*4 + rr ----
    // A = W2 frag (row nt*16+l16, global bf16), B = node frag
    f32x4 acc[8];
    #pragma unroll
    for (int nt = 0; nt < 8; nt++) acc[nt] = f32x4{0.f, 0.f, 0.f, 0.f};
    #pragma unroll
    for (int ks = 0; ks < 4; ks++) {
        #pragma unroll
        for (int nt = 0; nt < 8; nt++) {
            s16x8 wfr = *reinterpret_cast<const s16x8*>(
                w2bf + (size_t)(nt * 16 + l16) * H_DIM + lq * 8 + ks * 32);
            acc[nt] = __builtin_amdgcn_mfma_f32_16x16x32_bf16(wfr, af[ks], acc[nt], 0, 0, 0);
        }
    }

    // --- alpha: sum_h sigmoid(z + a_g[sgl][h]) * q_w[h] ------------------
    const float* agrow = a_g + (size_t)sgl * H_DIM + lq * 4;
    float pp0 = 0.f, pp1 = 0.f, pp2 = 0.f, pp3 = 0.f;
    #pragma unroll
    for (int nt = 0; nt < 8; nt++) {
        float4 q4 = *reinterpret_cast<const float4*>(q_w + nt * 16 + lq * 4);
        float4 a4 = *reinterpret_cast<const float4*>(agrow + nt * 16);
        float z0 = acc[nt][0] + a4.x;
        float z1 = acc[nt][1] + a4.y;
        float z2 = acc[nt][2] + a4.z;
        float z3 = acc[nt][3] + a4.w;
        pp0 += q4.x * __builtin_amdgcn_rcpf(1.f + __expf(-z0));
        pp1 += q4.y * __builtin_amdgcn_rcpf(1.f + __expf(-z1));
        pp2 += q4.z * __builtin_amdgcn_rcpf(1.f + __expf(-z2));
        pp3 += q4.w * __builtin_amdgcn_rcpf(1.f + __expf(-z3));
    }
    float p = (pp0 + pp1) + (pp2 + pp3);
    p += __shfl_xor(p, 16, 64);
    p += __shfl_xor(p, 32, 64);
    const float coefl = ncl * (p + qb0);   // coef for node row l16, all lanes

    // --- identity-MFMA transpose: accT[ks][b][rr] = node[lq*4+rr][ks*32+b*16+l16]
    s16x8 ib[2];
    #pragma unroll
    for (int b = 0; b < 2; b++) {
        int kk = l16 + 16 * b;
        #pragma unroll
        for (int e = 0; e < 8; e++)
            ib[b][e] = (kk == lq * 8 + e) ? (short)0x3F80 : (short)0;
    }
    f32x4 accT[4][2];
    #pragma unroll
    for (int ks = 0; ks < 4; ks++)
        #pragma unroll
        for (int b = 0; b < 2; b++)
            accT[ks][b] = __builtin_amdgcn_mfma_f32_16x16x32_bf16(
                              af[ks], ib[b], f32x4{0.f, 0.f, 0.f, 0.f}, 0, 0, 0);

    // --- segmented sum over the wave's 16 rows, run by run ---------------
    int r0 = 0;
    while (r0 < 16) {
        const int cur = __shfl(sgl, r0, 64);                 // wave-uniform
        unsigned long long diff = __ballot(sgl != cur) & 0xFFFFull;
        diff &= ~((1ull << r0) - 1ull);
        const int r1 = diff ? (int)__builtin_ctzll(diff) : 16;

        const float cmask = (sgl == cur) ? coefl : 0.f;      // masked coef of row l16
        float cm[4];
        #pragma unroll
        for (int rr = 0; rr < 4; rr++)
            cm[rr] = __shfl(cmask, lq * 4 + rr, 64);

        #pragma unroll
        for (int ks = 0; ks < 4; ks++) {
            #pragma unroll
            for (int b = 0; b < 2; b++) {
                float s = cm[0] * accT[ks][b][0] + cm[1] * accT[ks][b][1]
                        + cm[2] * accT[ks][b][2] + cm[3] * accT[ks][b][3];
                s += __shfl_xor(s, 16, 64);
                s += __shfl_xor(s, 32, 64);
                if (lq == 0)
                    atomicAdd(s_g + (size_t)cur * H_DIM + ks * 32 + b * 16 + l16, s);
            }
        }
        r0 = r1;
    }
}

// ---------------- K3: s_h = [v_n | s_g] @ W3^T + W3_b ------------------
__global__ __launch_bounds__(128) void k3_out(
    const float* __restrict__ node_emb,
    const int*   __restrict__ last_idx,
    const float* __restrict__ s_g,
    const float* __restrict__ W3w,
    const float* __restrict__ W3b,
    float* __restrict__ out)
{
    __shared__ float cat[8][2 * H_DIM];
    const int tid = threadIdx.x;
    const int g0  = blockIdx.x * 8;
    #pragma unroll
    for (int g = 0; g < 8; g++) {
        cat[g][tid]         = node_emb[(size_t)last_idx[g0 + g] * H_DIM + tid];
        cat[g][H_DIM + tid] = s_g[(size_t)(g0 + g) * H_DIM + tid];
    }
    __syncthreads();
    float acc[8];
    float b = W3b[tid];
    #pragma unroll
    for (int g = 0; g < 8; g++) acc[g] = b;
    const float* wrow = W3w + (size_t)tid * (2 * H_DIM);
    for (int k = 0; k < 2 * H_DIM; k += 4) {
        float4 w = *reinterpret_cast<const float4*>(wrow + k);
        #pragma unroll
        for (int g = 0; g < 8; g++)
            acc[g] += w.x * cat[g][k] + w.y * cat[g][k+1]
                    + w.z * cat[g][k+2] + w.w * cat[g][k+3];
    }
    #pragma unroll
    for (int g = 0; g < 8; g++)
        out[(size_t)(g0 + g) * H_DIM + tid] = acc[g];
}

extern "C" void kernel_launch(void* const* d_in, const int* in_sizes, int n_in,
                              void* d_out, int out_size, void* d_ws, size_t ws_size,
                              hipStream_t stream) {
    const float* node_emb  = (const float*)d_in[0];
    const float* num_count = (const float*)d_in[1];
    // d_in[2] sections: unused
    const int*   seg_ids   = (const int*)d_in[3];
    const int*   last_idx  = (const int*)d_in[4];
    // d_in[5..8] unused
    const float* W1w = (const float*)d_in[9];
    const float* W1b = (const float*)d_in[10];
    const float* W2w = (const float*)d_in[11];
    const float* W2b = (const float*)d_in[12];
    const float* qw  = (const float*)d_in[13];
    const float* qb  = (const float*)d_in[14];
    const float* W3w = (const float*)d_in[15];
    const float* W3b = (const float*)d_in[16];
    float* out = (float*)d_out;

    char* ws = (char*)d_ws;
    float* a_g = (float*)(ws);                          // 4 MB
    float* s_g = (float*)(ws + (4u << 20));             // 4 MB
    unsigned short* w2bf = (unsigned short*)(ws + (8u << 20));   // 32 KB

    k0_w2   <<<64,          256, 0, stream>>>(W2w, w2bf);
    k1_ag   <<<NGRAPH / 4,  128, 0, stream>>>(node_emb, last_idx, W1w, W1b, W2b, a_g, s_g);
    k2_fused<<<NTOTAL / 64, 256, 0, stream>>>(node_emb, num_count, seg_ids, a_g,
                                              w2bf, qw, qb, s_g);
    k3_out  <<<NGRAPH / 8,  128, 0, stream>>>(node_emb, last_idx, s_g, W3w, W3b, out);
}

// Round 9
// 110.348 us; speedup vs baseline: 1.7153x; 1.7153x over previous
//
#include <hip/hip_runtime.h>
#include <hip/hip_bf16.h>

// Problem constants (fixed by the reference setup)
#define H_DIM  128
#define NGRAPH 8192
#define NTOTAL 409600
#define NJOBS  (NTOTAL / 16)     // 25600 16-node jobs
#define NBLK   256
#define WPB    6                 // waves per block
#define NWAVES (NBLK * WPB)      // 1536

typedef __attribute__((ext_vector_type(8))) short    s16x8;   // 8 bf16
typedef __attribute__((ext_vector_type(4))) float    f32x4;   // MFMA accumulator
typedef __attribute__((ext_vector_type(4))) unsigned u32x4;

__device__ __forceinline__ unsigned short f2bf(float f) {
    unsigned int u = __float_as_uint(f);
    unsigned int r = u + 0x7fffu + ((u >> 16) & 1u);   // RNE
    return (unsigned short)(r >> 16);
}

// async global->LDS, 16B per lane; LDS dest = wave-uniform base + lane*16
__device__ __forceinline__ void gload_lds16(const void* g, void* l) {
    __builtin_amdgcn_global_load_lds(
        (const __attribute__((address_space(1))) unsigned int*)g,
        (__attribute__((address_space(3))) unsigned int*)l,
        16, 0, 0);
}

// ---------------- K0: W2 f32 -> bf16 (row-major [h][k]) ----------------
__global__ void k0_w2(const float* __restrict__ W2w, unsigned short* __restrict__ w2bf) {
    int i = blockIdx.x * 256 + threadIdx.x;   // grid covers exactly 128*128
    w2bf[i] = f2bf(W2w[i]);
}

// ---------------- K1: a_g = v_n @ W1^T + (W1_b + W2_b); zero s_g -------
__global__ __launch_bounds__(128) void k1_ag(
    const float* __restrict__ node_emb,
    const int*   __restrict__ last_idx,
    const float* __restrict__ W1w,
    const float* __restrict__ W1b,
    const float* __restrict__ W2b,
    float* __restrict__ a_g,
    float* __restrict__ s_g)
{
    __shared__ float vn[4][H_DIM];
    const int tid = threadIdx.x;
    const int g0  = blockIdx.x * 4;
    #pragma unroll
    for (int g = 0; g < 4; g++) {
        int li = last_idx[g0 + g];
        vn[g][tid] = node_emb[(size_t)li * H_DIM + tid];
        s_g[(size_t)(g0 + g) * H_DIM + tid] = 0.f;   // zero-init for k2 atomics
    }
    __syncthreads();
    float b = W1b[tid] + W2b[tid];
    float a0 = b, a1 = b, a2 = b, a3 = b;
    const float* wrow = W1w + (size_t)tid * H_DIM;
    #pragma unroll 8
    for (int k = 0; k < H_DIM; k += 4) {
        float4 w = *reinterpret_cast<const float4*>(wrow + k);
        a0 += w.x * vn[0][k] + w.y * vn[0][k+1] + w.z * vn[0][k+2] + w.w * vn[0][k+3];
        a1 += w.x * vn[1][k] + w.y * vn[1][k+1] + w.z * vn[1][k+2] + w.w * vn[1][k+3];
        a2 += w.x * vn[2][k] + w.y * vn[2][k+1] + w.z * vn[2][k+2] + w.w * vn[2][k+3];
        a3 += w.x * vn[3][k] + w.y * vn[3][k+1] + w.z * vn[3][k+2] + w.w * vn[3][k+3];
    }
    a_g[(size_t)(g0 + 0) * H_DIM + tid] = a0;
    a_g[(size_t)(g0 + 1) * H_DIM + tid] = a1;
    a_g[(size_t)(g0 + 2) * H_DIM + tid] = a2;
    a_g[(size_t)(g0 + 3) * H_DIM + tid] = a3;
}

// ---------------- K2: DMA-pipelined fused alpha + segment-sum ----------
// 256 blocks x 384 threads (6 waves), 1 block/CU (128 KB LDS). Each wave
// owns a private 2x8KB node double-buffer; stages its NEXT 16-node job via
// global_load_lds while computing the current one. No loop barriers.
__global__ __launch_bounds__(384, 2) void k2_fused(
    const float* __restrict__ node_emb,
    const float* __restrict__ num_count,
    const int*   __restrict__ seg_ids,
    const float* __restrict__ a_g,
    const unsigned short* __restrict__ w2bf,
    const float* __restrict__ q_w,
    const float* __restrict__ q_b,
    float* __restrict__ s_g)
{
    __shared__ __align__(16) char ndbuf[WPB][2][8192];   // 96 KB, wave-private
    __shared__ __align__(16) char w2s[H_DIM * 256];      // 32 KB, swizzled

    const int tid = threadIdx.x;
    // --- stage W2 bf16 -> LDS (once), XOR swizzled ---
    {
        const uint4* wsrc = reinterpret_cast<const uint4*>(w2bf);
        #pragma unroll
        for (int i = 0; i < 6; i++) {
            int c = i * 384 + tid;
            if (c < 2048) {
                uint4 v = wsrc[c];
                int byte = c << 4;
                int row  = byte >> 8;
                *reinterpret_cast<uint4*>(w2s + (byte ^ ((row & 7) << 4))) = v;
            }
        }
    }

    const int lane = tid & 63;
    const int wid  = tid >> 6;                 // 0..5
    const int l16 = lane & 15, lq = lane >> 4;
    const int gw = blockIdx.x * WPB + wid;     // global wave id
    const int j0 = (int)(((long)gw       * NJOBS) / NWAVES);
    const int j1 = (int)(((long)(gw + 1) * NJOBS) / NWAVES);

    // loop invariants: q_w fragments and identity B-fragments
    float qv[8][4];
    #pragma unroll
    for (int nt = 0; nt < 8; nt++) {
        float4 q4 = *reinterpret_cast<const float4*>(q_w + nt * 16 + lq * 4);
        qv[nt][0] = q4.x; qv[nt][1] = q4.y; qv[nt][2] = q4.z; qv[nt][3] = q4.w;
    }
    s16x8 ib[2];
    #pragma unroll
    for (int b = 0; b < 2; b++) {
        int kk = l16 + 16 * b;
        #pragma unroll
        for (int e = 0; e < 8; e++)
            ib[b][e] = (kk == lq * 8 + e) ? (short)0x3F80 : (short)0;
    }
    const float qb0 = q_b[0];

    char* bufA = &ndbuf[wid][0][0];
    char* bufB = &ndbuf[wid][1][0];

    // --- prologue: stage job j0 into bufA; preload its seg/nc ---
    {
        const char* gbase = (const char*)node_emb + (size_t)j0 * 16 * 512;
        #pragma unroll
        for (int i = 0; i < 8; i++) {
            int lin = i * 1024 + lane * 16;
            int src = lin ^ (((lin >> 9) & 7) << 4);   // pre-swizzled source
            gload_lds16(gbase + src, bufA + i * 1024);
        }
    }
    int   sgN = seg_ids[j0 * 16 + l16];
    float ncN = num_count[j0 * 16 + l16];

    __syncthreads();   // w2s visible (drains prologue staging too — one-time)

    #pragma unroll 1
    for (int j = j0; j < j1; j++) {
        // --- wait: current job's staging complete (issued a full phase ago)
        asm volatile("s_waitcnt vmcnt(0)" ::: "memory");
        __builtin_amdgcn_sched_barrier(0);

        const int   sgl = sgN;
        const float ncl = ncN;

        // --- a_g prefetch (graph known since last iter; hides under MFMA) ---
        const float* agrow = a_g + (size_t)sgl * H_DIM + lq * 4;
        float4 ag4[8];
        #pragma unroll
        for (int nt = 0; nt < 8; nt++)
            ag4[nt] = *reinterpret_cast<const float4*>(agrow + nt * 16);

        // --- read f32 node rows from swizzled LDS, cvt -> bf16 fragments ---
        s16x8 af[4];
        #pragma unroll
        for (int ks = 0; ks < 4; ks++) {
            int base = l16 * 512 + lq * 32 + ks * 128;
            float4 f0 = *reinterpret_cast<const float4*>(bufA + ( base        ^ ((l16 & 7) << 4)));
            float4 f1 = *reinterpret_cast<const float4*>(bufA + ((base + 16) ^ ((l16 & 7) << 4)));
            unsigned p0, p1, p2, p3;
            asm("v_cvt_pk_bf16_f32 %0, %1, %2" : "=v"(p0) : "v"(f0.x), "v"(f0.y));
            asm("v_cvt_pk_bf16_f32 %0, %1, %2" : "=v"(p1) : "v"(f0.z), "v"(f0.w));
            asm("v_cvt_pk_bf16_f32 %0, %1, %2" : "=v"(p2) : "v"(f1.x), "v"(f1.y));
            asm("v_cvt_pk_bf16_f32 %0, %1, %2" : "=v"(p3) : "v"(f1.z), "v"(f1.w));
            union { u32x4 u; s16x8 s; } cv;
            cv.u = u32x4{p0, p1, p2, p3};
            af[ks] = cv.s;
        }

        // --- issue NEXT job's staging into the other buffer (wave-private) ---
        if (j + 1 < j1) {
            const char* gbase = (const char*)node_emb + (size_t)(j + 1) * 16 * 512;
            #pragma unroll
            for (int i = 0; i < 8; i++) {
                int lin = i * 1024 + lane * 16;
                int src = lin ^ (((lin >> 9) & 7) << 4);
                gload_lds16(gbase + src, bufB + i * 1024);
            }
            sgN = seg_ids[(j + 1) * 16 + l16];
            ncN = num_count[(j + 1) * 16 + l16];
        }

        // --- swapped z-MFMA, C-init = a_g  (lane holds z[l16][h]+a_g[h]) ---
        f32x4 acc[8];
        #pragma unroll
        for (int nt = 0; nt < 8; nt++)
            acc[nt] = f32x4{ag4[nt].x, ag4[nt].y, ag4[nt].z, ag4[nt].w};
        #pragma unroll
        for (int ks = 0; ks < 4; ks++) {
            #pragma unroll
            for (int nt = 0; nt < 8; nt++) {
                int row  = nt * 16 + l16;
                int byte = (row << 8) | ((lq * 8 + ks * 32) << 1);
                byte ^= (row & 7) << 4;
                s16x8 wfr = *reinterpret_cast<const s16x8*>(w2s + byte);
                acc[nt] = __builtin_amdgcn_mfma_f32_16x16x32_bf16(wfr, af[ks], acc[nt], 0, 0, 0);
            }
        }

        // --- alpha: sum_h sigmoid(z) * q_w[h]; 2-shfl reduce ---
        float pp0 = 0.f, pp1 = 0.f, pp2 = 0.f, pp3 = 0.f;
        #pragma unroll
        for (int nt = 0; nt < 8; nt++) {
            pp0 += qv[nt][0] * __builtin_amdgcn_rcpf(1.f + __expf(-acc[nt][0]));
            pp1 += qv[nt][1] * __builtin_amdgcn_rcpf(1.f + __expf(-acc[nt][1]));
            pp2 += qv[nt][2] * __builtin_amdgcn_rcpf(1.f + __expf(-acc[nt][2]));
            pp3 += qv[nt][3] * __builtin_amdgcn_rcpf(1.f + __expf(-acc[nt][3]));
        }
        float p = (pp0 + pp1) + (pp2 + pp3);
        p += __shfl_xor(p, 16, 64);
        p += __shfl_xor(p, 32, 64);
        const float coefl = ncl * (p + qb0);   // coef for node row l16

        // --- identity-MFMA transpose: accT[ks][b][rr] = node[lq*4+rr][...] ---
        f32x4 accT[4][2];
        #pragma unroll
        for (int ks = 0; ks < 4; ks++)
            #pragma unroll
            for (int b = 0; b < 2; b++)
                accT[ks][b] = __builtin_amdgcn_mfma_f32_16x16x32_bf16(
                                  af[ks], ib[b], f32x4{0.f, 0.f, 0.f, 0.f}, 0, 0, 0);

        // --- segmented sum over the job's 16 rows, run by run --------------
        int r0 = 0;
        while (r0 < 16) {
            const int cur = __shfl(sgl, r0, 64);                 // wave-uniform
            unsigned long long diff = __ballot(sgl != cur) & 0xFFFFull;
            diff &= ~((1ull << r0) - 1ull);
            const int r1 = diff ? (int)__builtin_ctzll(diff) : 16;

            const float cmask = (sgl == cur) ? coefl : 0.f;
            float cm[4];
            #pragma unroll
            for (int rr = 0; rr < 4; rr++)
                cm[rr] = __shfl(cmask, lq * 4 + rr, 64);

            #pragma unroll
            for (int ks = 0; ks < 4; ks++) {
                #pragma unroll
                for (int b = 0; b < 2; b++) {
                    float s = cm[0] * accT[ks][b][0] + cm[1] * accT[ks][b][1]
                            + cm[2] * accT[ks][b][2] + cm[3] * accT[ks][b][3];
                    s += __shfl_xor(s, 16, 64);
                    s += __shfl_xor(s, 32, 64);
                    if (lq == 0)
                        atomicAdd(s_g + (size_t)cur * H_DIM + ks * 32 + b * 16 + l16, s);
                }
            }
            r0 = r1;
        }

        // swap buffers (pointer swap keeps indexing static)
        char* t = bufA; bufA = bufB; bufB = t;
    }
}

// ---------------- K3: s_h = [v_n | s_g] @ W3^T + W3_b ------------------
__global__ __launch_bounds__(128) void k3_out(
    const float* __restrict__ node_emb,
    const int*   __restrict__ last_idx,
    const float* __restrict__ s_g,
    const float* __restrict__ W3w,
    const float* __restrict__ W3b,
    float* __restrict__ out)
{
    __shared__ float cat[8][2 * H_DIM];
    const int tid = threadIdx.x;
    const int g0  = blockIdx.x * 8;
    #pragma unroll
    for (int g = 0; g < 8; g++) {
        cat[g][tid]         = node_emb[(size_t)last_idx[g0 + g] * H_DIM + tid];
        cat[g][H_DIM + tid] = s_g[(size_t)(g0 + g) * H_DIM + tid];
    }
    __syncthreads();
    float acc[8];
    float b = W3b[tid];
    #pragma unroll
    for (int g = 0; g < 8; g++) acc[g] = b;
    const float* wrow = W3w + (size_t)tid * (2 * H_DIM);
    for (int k = 0; k < 2 * H_DIM; k += 4) {
        float4 w = *reinterpret_cast<const float4*>(wrow + k);
        #pragma unroll
        for (int g = 0; g < 8; g++)
            acc[g] += w.x * cat[g][k] + w.y * cat[g][k+1]
                    + w.z * cat[g][k+2] + w.w * cat[g][k+3];
    }
    #pragma unroll
    for (int g = 0; g < 8; g++)
        out[(size_t)(g0 + g) * H_DIM + tid] = acc[g];
}

extern "C" void kernel_launch(void* const* d_in, const int* in_sizes, int n_in,
                              void* d_out, int out_size, void* d_ws, size_t ws_size,
                              hipStream_t stream) {
    const float* node_emb  = (const float*)d_in[0];
    const float* num_count = (const float*)d_in[1];
    // d_in[2] sections: unused
    const int*   seg_ids   = (const int*)d_in[3];
    const int*   last_idx  = (const int*)d_in[4];
    // d_in[5..8] unused
    const float* W1w = (const float*)d_in[9];
    const float* W1b = (const float*)d_in[10];
    const float* W2w = (const float*)d_in[11];
    const float* W2b = (const float*)d_in[12];
    const float* qw  = (const float*)d_in[13];
    const float* qb  = (const float*)d_in[14];
    const float* W3w = (const float*)d_in[15];
    const float* W3b = (const float*)d_in[16];
    float* out = (float*)d_out;

    char* ws = (char*)d_ws;
    float* a_g = (float*)(ws);                          // 4 MB
    float* s_g = (float*)(ws + (4u << 20));             // 4 MB
    unsigned short* w2bf = (unsigned short*)(ws + (8u << 20));   // 32 KB

    k0_w2   <<<64,         256, 0, stream>>>(W2w, w2bf);
    k1_ag   <<<NGRAPH / 4, 128, 0, stream>>>(node_emb, last_idx, W1w, W1b, W2b, a_g, s_g);
    k2_fused<<<NBLK,       384, 0, stream>>>(node_emb, num_count, seg_ids, a_g,
                                             w2bf, qw, qb, s_g);
    k3_out  <<<NGRAPH / 8, 128, 0, stream>>>(node_emb, last_idx, s_g, W3w, W3b, out);
}

// Round 10
// 107.198 us; speedup vs baseline: 1.7657x; 1.0294x over previous
//
#include <hip/hip_runtime.h>
#include <hip/hip_bf16.h>

// Problem constants (fixed by the reference setup)
#define H_DIM  128
#define NGRAPH 8192
#define NTOTAL 409600
#define NBLK2  (NTOTAL / 128)     // 3200 blocks of 8 waves x 16 nodes

#define NLOG2E -1.4426950408889634f

typedef __attribute__((ext_vector_type(8))) short    s16x8;   // 8 bf16
typedef __attribute__((ext_vector_type(4))) float    f32x4;   // MFMA accumulator
typedef __attribute__((ext_vector_type(4))) unsigned u32x4;

__device__ __forceinline__ unsigned short f2bf(float f) {
    unsigned int u = __float_as_uint(f);
    unsigned int r = u + 0x7fffu + ((u >> 16) & 1u);   // RNE
    return (unsigned short)(r >> 16);
}

// ---------------- K0: w2bf = bf16(-log2e * W2), row-major [h][k] -------
__global__ void k0_w2(const float* __restrict__ W2w, unsigned short* __restrict__ w2bf) {
    int i = blockIdx.x * 256 + threadIdx.x;   // grid covers exactly 128*128
    w2bf[i] = f2bf(NLOG2E * W2w[i]);
}

// ---------------- K1: a_g = -log2e*(v_n @ W1^T + W1_b + W2_b); zero s_g
__global__ __launch_bounds__(128) void k1_ag(
    const float* __restrict__ node_emb,
    const int*   __restrict__ last_idx,
    const float* __restrict__ W1w,
    const float* __restrict__ W1b,
    const float* __restrict__ W2b,
    float* __restrict__ a_g,
    float* __restrict__ s_g)
{
    __shared__ float vn[4][H_DIM];
    const int tid = threadIdx.x;
    const int g0  = blockIdx.x * 4;
    #pragma unroll
    for (int g = 0; g < 4; g++) {
        int li = last_idx[g0 + g];
        vn[g][tid] = node_emb[(size_t)li * H_DIM + tid];
        s_g[(size_t)(g0 + g) * H_DIM + tid] = 0.f;   // zero-init for k2 atomics
    }
    __syncthreads();
    float b = W1b[tid] + W2b[tid];
    float a0 = b, a1 = b, a2 = b, a3 = b;
    const float* wrow = W1w + (size_t)tid * H_DIM;
    #pragma unroll 8
    for (int k = 0; k < H_DIM; k += 4) {
        float4 w = *reinterpret_cast<const float4*>(wrow + k);
        a0 += w.x * vn[0][k] + w.y * vn[0][k+1] + w.z * vn[0][k+2] + w.w * vn[0][k+3];
        a1 += w.x * vn[1][k] + w.y * vn[1][k+1] + w.z * vn[1][k+2] + w.w * vn[1][k+3];
        a2 += w.x * vn[2][k] + w.y * vn[2][k+1] + w.z * vn[2][k+2] + w.w * vn[2][k+3];
        a3 += w.x * vn[3][k] + w.y * vn[3][k+1] + w.z * vn[3][k+2] + w.w * vn[3][k+3];
    }
    a_g[(size_t)(g0 + 0) * H_DIM + tid] = NLOG2E * a0;
    a_g[(size_t)(g0 + 1) * H_DIM + tid] = NLOG2E * a1;
    a_g[(size_t)(g0 + 2) * H_DIM + tid] = NLOG2E * a2;
    a_g[(size_t)(g0 + 3) * H_DIM + tid] = NLOG2E * a3;
}

// ---------------- K2: one-shot fused alpha + segment-sum ---------------
// 3200 blocks x 512 threads (8 waves). One barrier (W2 stage). Each wave
// owns 16 nodes. sigmoid via prescaled exp2: sig = rcp(1 + exp2(acc)).
__global__ __launch_bounds__(512, 6) void k2_fused(
    const float* __restrict__ node_emb,
    const float* __restrict__ num_count,
    const int*   __restrict__ seg_ids,
    const float* __restrict__ a_g,
    const unsigned short* __restrict__ w2bf,
    const float* __restrict__ q_w,
    const float* __restrict__ q_b,
    float* __restrict__ s_g)
{
    __shared__ __align__(16) char w2s[H_DIM * 256];   // 32 KB, swizzled

    const int tid = threadIdx.x;
    // --- stage W2 bf16 -> LDS (once per block), XOR swizzled ---
    {
        const uint4* wsrc = reinterpret_cast<const uint4*>(w2bf);
        #pragma unroll
        for (int i = 0; i < 4; i++) {
            int c = i * 512 + tid;
            uint4 v = wsrc[c];
            int byte = c << 4;
            int row  = byte >> 8;
            *reinterpret_cast<uint4*>(w2s + (byte ^ ((row & 7) << 4))) = v;
        }
    }

    // XCD-aware bijective swizzle (3200 % 8 == 0 -> 400 chunks per XCD)
    const int bid = (int)blockIdx.x;
    const int swz = (bid & 7) * (NBLK2 / 8) + (bid >> 3);

    const int lane = tid & 63;
    const int wid  = tid >> 6;                 // 0..7
    const int l16 = lane & 15, lq = lane >> 4;
    const int nb  = (swz * 8 + wid) * 16;      // this wave's 16 nodes

    // --- per-row scalars (row = l16) ---
    const int   sgl = seg_ids[nb + l16];
    const float ncl = num_count[nb + l16];
    const float qb0 = q_b[0];

    // --- a_g row (prescaled), h = nt*16 + lq*4 + rr: becomes MFMA C-init ---
    const float* agrow = a_g + (size_t)sgl * H_DIM + lq * 4;
    f32x4 acc[8];
    #pragma unroll
    for (int nt = 0; nt < 8; nt++) {
        float4 a4 = *reinterpret_cast<const float4*>(agrow + nt * 16);
        acc[nt] = f32x4{a4.x, a4.y, a4.z, a4.w};
    }

    // --- node fragments: row l16, cols lq*8 + ks*32 .. +7 (f32 -> bf16) ---
    s16x8 af[4];
    const float* nrow = node_emb + (size_t)(nb + l16) * H_DIM + lq * 8;
    #pragma unroll
    for (int ks = 0; ks < 4; ks++) {
        float4 f0 = *reinterpret_cast<const float4*>(nrow + ks * 32);
        float4 f1 = *reinterpret_cast<const float4*>(nrow + ks * 32 + 4);
        unsigned p0, p1, p2, p3;
        asm("v_cvt_pk_bf16_f32 %0, %1, %2" : "=v"(p0) : "v"(f0.x), "v"(f0.y));
        asm("v_cvt_pk_bf16_f32 %0, %1, %2" : "=v"(p1) : "v"(f0.z), "v"(f0.w));
        asm("v_cvt_pk_bf16_f32 %0, %1, %2" : "=v"(p2) : "v"(f1.x), "v"(f1.y));
        asm("v_cvt_pk_bf16_f32 %0, %1, %2" : "=v"(p3) : "v"(f1.z), "v"(f1.w));
        union { u32x4 u; s16x8 s; } cv;
        cv.u = u32x4{p0, p1, p2, p3};
        af[ks] = cv.s;
    }

    __syncthreads();   // w2s ready (only barrier)

    // --- swapped z-MFMA: lane holds z'[l16][h] = -log2e*(z+a_g) ----------
    #pragma unroll
    for (int ks = 0; ks < 4; ks++) {
        #pragma unroll
        for (int nt = 0; nt < 8; nt++) {
            int row  = nt * 16 + l16;
            int byte = (row << 8) | ((lq * 8 + ks * 32) << 1);
            byte ^= (row & 7) << 4;
            s16x8 wfr = *reinterpret_cast<const s16x8*>(w2s + byte);
            acc[nt] = __builtin_amdgcn_mfma_f32_16x16x32_bf16(wfr, af[ks], acc[nt], 0, 0, 0);
        }
    }

    // --- alpha: sum_h q_w[h] / (1 + exp2(z')); 2-shfl reduce -------------
    float pp0 = 0.f, pp1 = 0.f, pp2 = 0.f, pp3 = 0.f;
    #pragma unroll
    for (int nt = 0; nt < 8; nt++) {
        float4 q4 = *reinterpret_cast<const float4*>(q_w + nt * 16 + lq * 4);
        pp0 += q4.x * __builtin_amdgcn_rcpf(1.f + __builtin_amdgcn_exp2f(acc[nt][0]));
        pp1 += q4.y * __builtin_amdgcn_rcpf(1.f + __builtin_amdgcn_exp2f(acc[nt][1]));
        pp2 += q4.z * __builtin_amdgcn_rcpf(1.f + __builtin_amdgcn_exp2f(acc[nt][2]));
        pp3 += q4.w * __builtin_amdgcn_rcpf(1.f + __builtin_amdgcn_exp2f(acc[nt][3]));
    }
    float p = (pp0 + pp1) + (pp2 + pp3);
    p += __shfl_xor(p, 16, 64);
    p += __shfl_xor(p, 32, 64);
    const float coefl = ncl * (p + qb0);   // coef for node row l16, all lanes

    // --- identity-MFMA transpose: accT[ks][b][rr] = node[lq*4+rr][...] ---
    s16x8 ib[2];
    #pragma unroll
    for (int b = 0; b < 2; b++) {
        int kk = l16 + 16 * b;
        #pragma unroll
        for (int e = 0; e < 8; e++)
            ib[b][e] = (kk == lq * 8 + e) ? (short)0x3F80 : (short)0;
    }
    f32x4 accT[4][2];
    #pragma unroll
    for (int ks = 0; ks < 4; ks++)
        #pragma unroll
        for (int b = 0; b < 2; b++)
            accT[ks][b] = __builtin_amdgcn_mfma_f32_16x16x32_bf16(
                              af[ks], ib[b], f32x4{0.f, 0.f, 0.f, 0.f}, 0, 0, 0);

    // --- segmented sum over the wave's 16 rows, run by run ---------------
    int r0 = 0;
    while (r0 < 16) {
        const int cur = __shfl(sgl, r0, 64);                 // wave-uniform
        unsigned long long diff = __ballot(sgl != cur) & 0xFFFFull;
        diff &= ~((1ull << r0) - 1ull);
        const int r1 = diff ? (int)__builtin_ctzll(diff) : 16;

        const float cmask = (sgl == cur) ? coefl : 0.f;      // masked coef of row l16
        float cm[4];
        #pragma unroll
        for (int rr = 0; rr < 4; rr++)
            cm[rr] = __shfl(cmask, lq * 4 + rr, 64);

        #pragma unroll
        for (int ks = 0; ks < 4; ks++) {
            #pragma unroll
            for (int b = 0; b < 2; b++) {
                float s = cm[0] * accT[ks][b][0] + cm[1] * accT[ks][b][1]
                        + cm[2] * accT[ks][b][2] + cm[3] * accT[ks][b][3];
                s += __shfl_xor(s, 16, 64);
                s += __shfl_xor(s, 32, 64);
                if (lq == 0)
                    atomicAdd(s_g + (size_t)cur * H_DIM + ks * 32 + b * 16 + l16, s);
            }
        }
        r0 = r1;
    }
}

// ---------------- K3: s_h = [v_n | s_g] @ W3^T + W3_b ------------------
__global__ __launch_bounds__(128) void k3_out(
    const float* __restrict__ node_emb,
    const int*   __restrict__ last_idx,
    const float* __restrict__ s_g,
    const float* __restrict__ W3w,
    const float* __restrict__ W3b,
    float* __restrict__ out)
{
    __shared__ float cat[8][2 * H_DIM];
    const int tid = threadIdx.x;
    const int g0  = blockIdx.x * 8;
    #pragma unroll
    for (int g = 0; g < 8; g++) {
        cat[g][tid]         = node_emb[(size_t)last_idx[g0 + g] * H_DIM + tid];
        cat[g][H_DIM + tid] = s_g[(size_t)(g0 + g) * H_DIM + tid];
    }
    __syncthreads();
    float acc[8];
    float b = W3b[tid];
    #pragma unroll
    for (int g = 0; g < 8; g++) acc[g] = b;
    const float* wrow = W3w + (size_t)tid * (2 * H_DIM);
    for (int k = 0; k < 2 * H_DIM; k += 4) {
        float4 w = *reinterpret_cast<const float4*>(wrow + k);
        #pragma unroll
        for (int g = 0; g < 8; g++)
            acc[g] += w.x * cat[g][k] + w.y * cat[g][k+1]
                    + w.z * cat[g][k+2] + w.w * cat[g][k+3];
    }
    #pragma unroll
    for (int g = 0; g < 8; g++)
        out[(size_t)(g0 + g) * H_DIM + tid] = acc[g];
}

extern "C" void kernel_launch(void* const* d_in, const int* in_sizes, int n_in,
                              void* d_out, int out_size, void* d_ws, size_t ws_size,
                              hipStream_t stream) {
    const float* node_emb  = (const float*)d_in[0];
    const float* num_count = (const float*)d_in[1];
    // d_in[2] sections: unused
    const int*   seg_ids   = (const int*)d_in[3];
    const int*   last_idx  = (const int*)d_in[4];
    // d_in[5..8] unused
    const float* W1w = (const float*)d_in[9];
    const float* W1b = (const float*)d_in[10];
    const float* W2w = (const float*)d_in[11];
    const float* W2b = (const float*)d_in[12];
    const float* qw  = (const float*)d_in[13];
    const float* qb  = (const float*)d_in[14];
    const float* W3w = (const float*)d_in[15];
    const float* W3b = (const float*)d_in[16];
    float* out = (float*)d_out;

    char* ws = (char*)d_ws;
    float* a_g = (float*)(ws);                          // 4 MB
    float* s_g = (float*)(ws + (4u << 20));             // 4 MB
    unsigned short* w2bf = (unsigned short*)(ws + (8u << 20));   // 32 KB

    k0_w2   <<<64,         256, 0, stream>>>(W2w, w2bf);
    k1_ag   <<<NGRAPH / 4, 128, 0, stream>>>(node_emb, last_idx, W1w, W1b, W2b, a_g, s_g);
    k2_fused<<<NBLK2,      512, 0, stream>>>(node_emb, num_count, seg_ids, a_g,
                                             w2bf, qw, qb, s_g);
    k3_out  <<<NGRAPH / 8, 128, 0, stream>>>(node_emb, last_idx, s_g, W3w, W3b, out);
}